// Round 20
// baseline (139.938 us; speedup 1.0000x reference)
//
#include <hip/hip_runtime.h>
#include <stdint.h>

#define NRB 13824
#define NDB 1728
#define EDIM 512
#define SPLIT 18
#define DPB (NDB/SPLIT)   // 96 domains per block
#define TILES (DPB/32)    // 3

typedef __attribute__((ext_vector_type(8))) _Float16 h8;
typedef __attribute__((ext_vector_type(4))) _Float16 hh4;
typedef __attribute__((ext_vector_type(4))) float f4;
typedef __attribute__((ext_vector_type(4))) unsigned short us4;

typedef __attribute__((address_space(3))) void lds_void;
typedef const __attribute__((address_space(1))) void gbl_void;

#define MFMA(a,b,c) __builtin_amdgcn_mfma_f32_16x16x32_f16(a,b,c,0,0,0)

static __device__ __forceinline__ ushort f2h(float f){
  union { _Float16 h; ushort u; } cv;
  cv.h = (_Float16)f;
  return cv.u;
}

static __device__ __forceinline__ float tanh_fast(float x){
  float ax = __builtin_fabsf(x);
  float t = __builtin_amdgcn_exp2f(ax * -2.8853900817779268f); // exp(-2ax)
  float r = (1.0f - t) * __builtin_amdgcn_rcpf(1.0f + t);
  return __builtin_copysignf(r, x);
}

// ---------------- prep (bases->fp16, weights concat+transpose, V transpose)
__global__ void prep_kernel(
    const float* __restrict__ pooled,
    const float* __restrict__ rlat, const float* __restrict__ dlat,
    const float* __restrict__ rpos, const float* __restrict__ dpos,
    const float* __restrict__ Wrp, const float* __restrict__ brp,
    const float* __restrict__ Wdp, const float* __restrict__ bdp,
    const float* __restrict__ Wrc, const float* __restrict__ brc,
    const float* __restrict__ Wdc, const float* __restrict__ bdc,
    const float* __restrict__ Wro, const float* __restrict__ bro,
    const float* __restrict__ Wdo2, const float* __restrict__ bdo2,
    ushort* __restrict__ rb, ushort* __restrict__ db,
    ushort* __restrict__ Wr_t, ushort* __restrict__ Wd_t,
    float* __restrict__ br_c, float* __restrict__ bd_c,
    ushort* __restrict__ dflt)
{
  const int NRE = NRB*EDIM, NDE = NDB*EDIM;
  int i0 = blockIdx.x*blockDim.x + threadIdx.x;
  int stride = gridDim.x*blockDim.x;
  for (int i=i0; i<NRE; i+=stride) rb[i] = f2h(rlat[i]+rpos[i]);
  for (int i=i0; i<NDE; i+=stride) db[i] = f2h(dlat[i]+dpos[i]);
  for (int i=i0; i<512*512; i+=stride){
    int n = i>>9, k = i&511;
    float vr = (n<256) ? Wrp[k*256+n] : ((n<384) ? Wrc[k*128+(n-256)] : Wro[k*128+(n-384)]);
    float vd = (n<256) ? Wdp[k*256+n] : ((n<384) ? Wdc[k*128+(n-256)] : Wdo2[k*128+(n-384)]);
    Wr_t[i] = f2h(vr); Wd_t[i] = f2h(vd);
  }
  for (int i=i0; i<512; i+=stride){
    br_c[i] = (i<256) ? brp[i] : ((i<384) ? brc[i-256] : bro[i-384]);
    bd_c[i] = (i<256) ? bdp[i] : ((i<384) ? bdc[i-256] : bdo2[i-384]);
  }
  for (int i=i0; i<64*NDB; i+=stride){
    int c = i/NDB, d = i - c*NDB;
    dflt[i] = f2h(pooled[d*64+c]);
  }
}

// ---------------- feats GEMM (fp16 A), both r- and d-side in one launch
__global__ __launch_bounds__(256) void gemm_feats(
    const ushort* __restrict__ Ar, const ushort* __restrict__ Btr,
    const float* __restrict__ biasr, ushort* __restrict__ Cr,
    const ushort* __restrict__ Ad, const ushort* __restrict__ Btd,
    const float* __restrict__ biasd, ushort* __restrict__ Cd)
{
  const ushort* A;  const ushort* Bt; const float* bias; ushort* C; int M; int bx;
  if ((int)blockIdx.x < 108){ A=Ar; Bt=Btr; bias=biasr; C=Cr; M=NRB; bx=blockIdx.x; }
  else                      { A=Ad; Bt=Btd; bias=biasd; C=Cd; M=NDB; bx=blockIdx.x-108; }

  __shared__ ushort As[128*32];
  __shared__ ushort Bs[128*32];
  const int tid = threadIdx.x;
  const int lane = tid & 63;
  const int wave = tid >> 6;
  const int l15 = lane & 15;
  const int lhi = lane >> 4;
  const int row0 = bx * 128;
  const int col0 = blockIdx.y * 128;
  const int wr = (wave>>1)*64;
  const int wc = (wave&1)*64;

  f4 acc[4][4] = {};
  char* Ab = (char*)As; char* Bb = (char*)Bs;

  for (int k0=0; k0<EDIM; k0+=32){
    __syncthreads();
    #pragma unroll
    for (int c=0;c<2;c++){
      int L = (tid + c*256)*16;
      int r = L>>6;
      int kb = L&63;
      int kbs = kb ^ ((r&3)<<4);
      int ra = row0 + r; if (ra > M-1) ra = M-1;
      const ushort* srcA = A + (size_t)ra*EDIM + k0 + (kbs>>1);
      const ushort* srcB = Bt + (size_t)(col0+r)*EDIM + k0 + (kbs>>1);
      __builtin_amdgcn_global_load_lds((gbl_void*)srcA, (lds_void*)(Ab + L), 16, 0, 0);
      __builtin_amdgcn_global_load_lds((gbl_void*)srcB, (lds_void*)(Bb + L), 16, 0, 0);
    }
    __syncthreads();
    h8 af[4], bf[4];
    #pragma unroll
    for (int i=0;i<4;i++){
      int rowa = wr + i*16 + l15;
      af[i] = *(const h8*)(Ab + (((rowa*64) + lhi*16) ^ ((rowa&3)<<4)));
      int rowb = wc + i*16 + l15;
      bf[i] = *(const h8*)(Bb + (((rowb*64) + lhi*16) ^ ((rowb&3)<<4)));
    }
    #pragma unroll
    for (int i=0;i<4;i++){
      #pragma unroll
      for (int j=0;j<4;j++){
        acc[i][j] = MFMA(af[i], bf[j], acc[i][j]);
      }
    }
  }

  #pragma unroll
  for (int j=0;j<4;j++){
    int col = col0 + wc + j*16 + l15;
    float bv = bias[col];
    #pragma unroll
    for (int i=0;i<4;i++){
      #pragma unroll
      for (int r=0;r<4;r++){
        int row = row0 + wr + i*16 + lhi*4 + r;
        if (row < M) C[(size_t)row*EDIM + col] = f2h(acc[i][j][r] + bv);
      }
    }
  }
}

// ---------------- fused attention: swapped-operand QK^T, lane-local softmax
// + global_load_lds DF stage, V hoist, setprio on QK MFMA cluster
__global__ __launch_bounds__(512, 2) void attn_kernel(
    const ushort* __restrict__ rfeat,   // [NRB][512]
    const ushort* __restrict__ dfeat,   // [NDB][512]
    const ushort* __restrict__ dflt,    // [64][NDB]
    ushort* __restrict__ accbuf,        // [SPLIT][NRB][64] fp16 partials
    float* __restrict__ mlbuf)          // [SPLIT][NRB][4]
{
  __shared__ ushort DF[DPB*512];  // 96 KB: whole split's domain tile, swizzled
  __shared__ ushort PT[8][16*32]; // per-wave P scratch, swizzled (8KB)

  const int tid  = threadIdx.x;
  const int wave = tid >> 6;
  const int lane = tid & 63;
  const int l15  = lane & 15;
  const int lhi  = lane >> 4;
  const int wrow = blockIdx.x*128 + wave*16;
  const int by   = blockIdx.y;           // split index
  const int dbase = by * DPB;

  constexpr float CL = 0.25f * 1.4426950408889634f;
  constexpr float CH = 0.08838834764831845f;

  char* DFb = (char*)DF;
  char* PTb = (char*)PT[wave];

  // stage the whole 96-domain tile via async global_load_lds:
  // each wave-issue covers exactly one dom row (dest wave-uniform + lane*16,
  // source column pre-XORed by the read-side swizzle -> ERRATA-21-safe)
  #pragma unroll
  for (int c=0;c<12;c++){
    int dom = wave + c*8;
    const ushort* src = dfeat + (size_t)(dbase+dom)*EDIM + ((lane*8) ^ ((dom&7)<<3));
    __builtin_amdgcn_global_load_lds((gbl_void*)src,
        (lds_void*)(DFb + dom*1024 + lane*16), 16, 0, 0);
  }

  // Q fragments in registers (qrow = wrow + l15)
  h8 q[16];
  {
    const ushort* qr = rfeat + (size_t)(wrow + l15)*EDIM + lhi*8;
    #pragma unroll
    for (int c=0;c<16;c++) q[c] = *(const h8*)(qr + c*32);
  }

  f4 acc[4] = {};
  float m = -1e30f, lsum = 0.f, offa = 0.f;
  const int sb = (lane & 48) + ((lane >> 4) << 2);  // gather src base: lhi*16 + lhi*4

  __syncthreads();   // vmcnt drain at barrier: DF ready; the ONLY block barrier

  for (int t=0; t<TILES; ++t){
    const int d0 = dbase + t*32;
    const int dloc = t*32;

    // hoist V fragment loads: L2 latency hides under QK
    h8 vb[4];
    #pragma unroll
    for (int nt=0; nt<4; nt++){
      int n = nt*16 + l15;
      vb[nt] = *(const h8*)(dflt + (size_t)n*NDB + d0 + lhi*8);
    }

    // swapped QK^T: A = domain fragment (dom = dloc+ct*16+l15), B = q
    f4 SL[2] = {}, SC[2] = {}, SO[2] = {};
    __builtin_amdgcn_s_setprio(1);
    #pragma unroll
    for (int ct=0; ct<2; ++ct){
      const int dom = dloc + ct*16 + l15;
      const int swz = (dom&7)<<4;
      const int base = dom*1024 + lhi*16;
      #pragma unroll
      for (int c=0;c<8;c++){
        h8 b = *(const h8*)(DFb + ((base + c*64) ^ swz));
        SL[ct] = MFMA(b, q[c], SL[ct]);
      }
      #pragma unroll
      for (int c=8;c<12;c++){
        h8 b = *(const h8*)(DFb + ((base + c*64) ^ swz));
        SC[ct] = MFMA(b, q[c], SC[ct]);
      }
      #pragma unroll
      for (int c=12;c<16;c++){
        h8 b = *(const h8*)(DFb + ((base + c*64) ^ swz));
        SO[ct] = MFMA(b, q[c], SO[ct]);
      }
    }
    __builtin_amdgcn_s_setprio(0);

    // lane-local softmax for qrow = l15 (8 doms per lane, spread over lhi)
    float lm = fmaxf(
        fmaxf(fmaxf(SL[0][0],SL[0][1]), fmaxf(SL[0][2],SL[0][3])),
        fmaxf(fmaxf(SL[1][0],SL[1][1]), fmaxf(SL[1][2],SL[1][3]))) * CL;
    lm = fmaxf(lm, __shfl_xor(lm, 16, 64));
    lm = fmaxf(lm, __shfl_xor(lm, 32, 64));   // exact row max, uniform across lhi
    float mn = fmaxf(m, lm);
    float al = __builtin_amdgcn_exp2f(m - mn);
    m = mn;
    lsum *= al; offa *= al;

    us4 w0, w1;
    #pragma unroll
    for (int r=0;r<4;r++){
      float p0 = __builtin_amdgcn_exp2f(SL[0][r]*CL - mn);
      float p1 = __builtin_amdgcn_exp2f(SL[1][r]*CL - mn);
      lsum += p0 + p1;
      float c0 = tanh_fast(SC[0][r]*CH)*1.8f;
      float c1 = tanh_fast(SC[1][r]*CH)*1.8f;
      float o0 = tanh_fast(SO[0][r]*CH);
      float o1 = tanh_fast(SO[1][r]*CH);
      offa += p0*o0 + p1*o1;
      w0[r] = f2h(p0*c0);
      w1[r] = f2h(p1*c1);
    }
    // PT write: row qrow=l15, doms ct*16+lhi*4..+4 as b64, swizzle ^((l15&3)<<4)
    {
      const int wbase = l15*64;
      const int xs = (l15&3)<<4;
      *(us4*)(PTb + ((wbase + lhi*8) ^ xs))      = w0;
      *(us4*)(PTb + ((wbase + 32 + lhi*8) ^ xs)) = w1;
    }

    // pin order: PT writes before PV PT-read (same-wave DS pipe is in-order)
    __builtin_amdgcn_sched_barrier(0);

    // PV: gather al for rows lhi*4+r, rescale acc, then MFMA
    {
      float alr[4];
      #pragma unroll
      for (int r=0;r<4;r++) alr[r] = __shfl(al, sb + r, 64);
      #pragma unroll
      for (int nt=0; nt<4; nt++){
        acc[nt][0]*=alr[0]; acc[nt][1]*=alr[1];
        acc[nt][2]*=alr[2]; acc[nt][3]*=alr[3];
      }
      h8 pa = *(const h8*)(PTb + ((l15*64 + lhi*16) ^ ((l15&3)<<4)));
      #pragma unroll
      for (int nt=0; nt<4; nt++){
        acc[nt] = MFMA(pa, vb[nt], acc[nt]);
      }
    }

    // pin order: PV PT-read stays before next iteration's PT writes
    __builtin_amdgcn_sched_barrier(0);
  }

  // epilogue: reduce l/off across lhi, store fp16 partials
  float ls = lsum, oa = offa;
  ls += __shfl_xor(ls, 16, 64); ls += __shfl_xor(ls, 32, 64);
  oa += __shfl_xor(oa, 16, 64); oa += __shfl_xor(oa, 32, 64);

  #pragma unroll
  for (int r=0;r<4;r++){
    int row = wrow + lhi*4 + r;
    size_t base = ((size_t)by*NRB + row)*64;
    #pragma unroll
    for (int nt=0; nt<4; nt++){
      accbuf[base + nt*16 + l15] = f2h(acc[nt][r]);
    }
  }
  if (lane < 16){
    size_t mo = ((size_t)by*NRB + wrow + l15)*4;
    mlbuf[mo+0] = m;
    mlbuf[mo+1] = ls;
    mlbuf[mo+2] = oa;
  }
}

// ---------------- combine partials (fp16 accbuf), 16 rows/block = 864 blocks
#define CROWS 16
__global__ __launch_bounds__(256) void combine_kernel(
    const ushort* __restrict__ accbuf,
    const float* __restrict__ mlbuf,
    float* __restrict__ out)
{
  __shared__ float wS[CROWS][SPLIT+1];
  __shared__ float c0S[CROWS], iTS[CROWS];
  const int rb = blockIdx.x;
  const int tid = threadIdx.x;

  if (tid < CROWS){
    int row = rb*CROWS + tid;
    float M = -1e30f;
    float m[SPLIT], l[SPLIT], o[SPLIT];
    #pragma unroll
    for (int s=0;s<SPLIT;s++){
      size_t off = ((size_t)s*NRB + row)*4;
      m[s]=mlbuf[off]; l[s]=mlbuf[off+1]; o[s]=mlbuf[off+2];
      M = fmaxf(M, m[s]);
    }
    float T=0.f, C=0.f;
    #pragma unroll
    for (int s=0;s<SPLIT;s++){
      float w = __builtin_amdgcn_exp2f(m[s]-M);
      wS[tid][s]=w; T += l[s]*w; C += o[s]*w;
    }
    c0S[tid]=C; iTS[tid]=1.0f/T;
  }
  __syncthreads();

  const int row_l = tid>>4;         // 0..15
  const int cb = (tid&15)*4;        // 0..60
  const int row = rb*CROWS + row_l;
  float res[4] = {};
  #pragma unroll
  for (int s=0;s<SPLIT;s++){
    float w = wS[row_l][s];
    hh4 v = *(const hh4*)(accbuf + ((size_t)s*NRB + row)*64 + cb);
    #pragma unroll
    for (int j=0;j<4;j++) res[j] += (float)v[j]*w;
  }
  float C = c0S[row_l], iT = iTS[row_l];
  #pragma unroll
  for (int j=0;j<4;j++) out[(size_t)row*64 + cb + j] = (res[j]+C)*iT;
}

extern "C" void kernel_launch(void* const* d_in, const int* in_sizes, int n_in,
                              void* d_out, int out_size, void* d_ws, size_t ws_size,
                              hipStream_t stream) {
  const float* pooled = (const float*)d_in[0];
  const float* rlat   = (const float*)d_in[1];
  const float* dlat   = (const float*)d_in[2];
  const float* rpos   = (const float*)d_in[3];
  const float* dpos   = (const float*)d_in[4];
  const float* Wrp    = (const float*)d_in[5];
  const float* brp    = (const float*)d_in[6];
  const float* Wdp    = (const float*)d_in[7];
  const float* bdp    = (const float*)d_in[8];
  const float* Wrc    = (const float*)d_in[9];
  const float* brc    = (const float*)d_in[10];
  const float* Wdc    = (const float*)d_in[11];
  const float* bdc    = (const float*)d_in[12];
  const float* Wro    = (const float*)d_in[13];
  const float* bro    = (const float*)d_in[14];
  const float* Wdo2   = (const float*)d_in[15];
  const float* bdo2   = (const float*)d_in[16];

  char* ws = (char*)d_ws;
  size_t off = 0;
  ushort* rb    = (ushort*)(ws + off); off += (size_t)NRB*EDIM*2;
  ushort* db    = (ushort*)(ws + off); off += (size_t)NDB*EDIM*2;
  ushort* Wr_t  = (ushort*)(ws + off); off += (size_t)512*512*2;
  ushort* Wd_t  = (ushort*)(ws + off); off += (size_t)512*512*2;
  float*  br_c  = (float*)(ws + off);  off += 512*4;
  float*  bd_c  = (float*)(ws + off);  off += 512*4;
  ushort* rfeat = (ushort*)(ws + off); off += (size_t)NRB*EDIM*2;
  ushort* dfeat = (ushort*)(ws + off); off += (size_t)NDB*EDIM*2;
  ushort* dflt  = (ushort*)(ws + off); off += (size_t)64*NDB*2;
  ushort* accb  = (ushort*)(ws + off); off += (size_t)SPLIT*NRB*64*2;
  float*  mlb   = (float*)(ws + off);  off += (size_t)SPLIT*NRB*4*4;

  prep_kernel<<<2048, 256, 0, stream>>>(pooled, rlat, dlat, rpos, dpos,
      Wrp, brp, Wdp, bdp, Wrc, brc, Wdc, bdc, Wro, bro, Wdo2, bdo2,
      rb, db, Wr_t, Wd_t, br_c, bd_c, dflt);

  gemm_feats<<<dim3(122,4), 256, 0, stream>>>(rb, Wr_t, br_c, rfeat,
                                              db, Wd_t, bd_c, dfeat);

  attn_kernel<<<dim3(108, SPLIT), 512, 0, stream>>>(rfeat, dfeat, dflt, accb, mlb);
  combine_kernel<<<NRB/CROWS, 256, 0, stream>>>(accb, mlb, (float*)d_out);
}

// Round 21
// 137.261 us; speedup vs baseline: 1.0195x; 1.0195x over previous
//
#include <hip/hip_runtime.h>
#include <stdint.h>

#define NRB 13824
#define NDB 1728
#define EDIM 512
#define SPLIT 18
#define DPB (NDB/SPLIT)   // 96 domains per block
#define TILES (DPB/32)    // 3

typedef __attribute__((ext_vector_type(8))) _Float16 h8;
typedef __attribute__((ext_vector_type(4))) _Float16 hh4;
typedef __attribute__((ext_vector_type(4))) float f4;
typedef __attribute__((ext_vector_type(4))) unsigned short us4;

typedef __attribute__((address_space(3))) void lds_void;
typedef const __attribute__((address_space(1))) void gbl_void;

#define MFMA(a,b,c) __builtin_amdgcn_mfma_f32_16x16x32_f16(a,b,c,0,0,0)

static __device__ __forceinline__ ushort f2h(float f){
  union { _Float16 h; ushort u; } cv;
  cv.h = (_Float16)f;
  return cv.u;
}

static __device__ __forceinline__ float tanh_fast(float x){
  float ax = __builtin_fabsf(x);
  float t = __builtin_amdgcn_exp2f(ax * -2.8853900817779268f); // exp(-2ax)
  float r = (1.0f - t) * __builtin_amdgcn_rcpf(1.0f + t);
  return __builtin_copysignf(r, x);
}

// ---------------- prep (bases->fp16, weights concat+transpose, V transpose)
__global__ void prep_kernel(
    const float* __restrict__ pooled,
    const float* __restrict__ rlat, const float* __restrict__ dlat,
    const float* __restrict__ rpos, const float* __restrict__ dpos,
    const float* __restrict__ Wrp, const float* __restrict__ brp,
    const float* __restrict__ Wdp, const float* __restrict__ bdp,
    const float* __restrict__ Wrc, const float* __restrict__ brc,
    const float* __restrict__ Wdc, const float* __restrict__ bdc,
    const float* __restrict__ Wro, const float* __restrict__ bro,
    const float* __restrict__ Wdo2, const float* __restrict__ bdo2,
    ushort* __restrict__ rb, ushort* __restrict__ db,
    ushort* __restrict__ Wr_t, ushort* __restrict__ Wd_t,
    float* __restrict__ br_c, float* __restrict__ bd_c,
    ushort* __restrict__ dflt)
{
  const int NRE = NRB*EDIM, NDE = NDB*EDIM;
  int i0 = blockIdx.x*blockDim.x + threadIdx.x;
  int stride = gridDim.x*blockDim.x;
  for (int i=i0; i<NRE; i+=stride) rb[i] = f2h(rlat[i]+rpos[i]);
  for (int i=i0; i<NDE; i+=stride) db[i] = f2h(dlat[i]+dpos[i]);
  for (int i=i0; i<512*512; i+=stride){
    int n = i>>9, k = i&511;
    float vr = (n<256) ? Wrp[k*256+n] : ((n<384) ? Wrc[k*128+(n-256)] : Wro[k*128+(n-384)]);
    float vd = (n<256) ? Wdp[k*256+n] : ((n<384) ? Wdc[k*128+(n-256)] : Wdo2[k*128+(n-384)]);
    Wr_t[i] = f2h(vr); Wd_t[i] = f2h(vd);
  }
  for (int i=i0; i<512; i+=stride){
    br_c[i] = (i<256) ? brp[i] : ((i<384) ? brc[i-256] : bro[i-384]);
    bd_c[i] = (i<256) ? bdp[i] : ((i<384) ? bdc[i-256] : bdo2[i-384]);
  }
  for (int i=i0; i<64*NDB; i+=stride){
    int c = i/NDB, d = i - c*NDB;
    dflt[i] = f2h(pooled[d*64+c]);
  }
}

// ---------------- feats GEMM (fp16 A), both r- and d-side in one launch
__global__ __launch_bounds__(256) void gemm_feats(
    const ushort* __restrict__ Ar, const ushort* __restrict__ Btr,
    const float* __restrict__ biasr, ushort* __restrict__ Cr,
    const ushort* __restrict__ Ad, const ushort* __restrict__ Btd,
    const float* __restrict__ biasd, ushort* __restrict__ Cd)
{
  const ushort* A;  const ushort* Bt; const float* bias; ushort* C; int M; int bx;
  if ((int)blockIdx.x < 108){ A=Ar; Bt=Btr; bias=biasr; C=Cr; M=NRB; bx=blockIdx.x; }
  else                      { A=Ad; Bt=Btd; bias=biasd; C=Cd; M=NDB; bx=blockIdx.x-108; }

  __shared__ ushort As[128*32];
  __shared__ ushort Bs[128*32];
  const int tid = threadIdx.x;
  const int lane = tid & 63;
  const int wave = tid >> 6;
  const int l15 = lane & 15;
  const int lhi = lane >> 4;
  const int row0 = bx * 128;
  const int col0 = blockIdx.y * 128;
  const int wr = (wave>>1)*64;
  const int wc = (wave&1)*64;

  f4 acc[4][4] = {};
  char* Ab = (char*)As; char* Bb = (char*)Bs;

  for (int k0=0; k0<EDIM; k0+=32){
    __syncthreads();
    #pragma unroll
    for (int c=0;c<2;c++){
      int L = (tid + c*256)*16;
      int r = L>>6;
      int kb = L&63;
      int kbs = kb ^ ((r&3)<<4);
      int ra = row0 + r; if (ra > M-1) ra = M-1;
      const ushort* srcA = A + (size_t)ra*EDIM + k0 + (kbs>>1);
      const ushort* srcB = Bt + (size_t)(col0+r)*EDIM + k0 + (kbs>>1);
      __builtin_amdgcn_global_load_lds((gbl_void*)srcA, (lds_void*)(Ab + L), 16, 0, 0);
      __builtin_amdgcn_global_load_lds((gbl_void*)srcB, (lds_void*)(Bb + L), 16, 0, 0);
    }
    __syncthreads();
    h8 af[4], bf[4];
    #pragma unroll
    for (int i=0;i<4;i++){
      int rowa = wr + i*16 + l15;
      af[i] = *(const h8*)(Ab + (((rowa*64) + lhi*16) ^ ((rowa&3)<<4)));
      int rowb = wc + i*16 + l15;
      bf[i] = *(const h8*)(Bb + (((rowb*64) + lhi*16) ^ ((rowb&3)<<4)));
    }
    #pragma unroll
    for (int i=0;i<4;i++){
      #pragma unroll
      for (int j=0;j<4;j++){
        acc[i][j] = MFMA(af[i], bf[j], acc[i][j]);
      }
    }
  }

  #pragma unroll
  for (int j=0;j<4;j++){
    int col = col0 + wc + j*16 + l15;
    float bv = bias[col];
    #pragma unroll
    for (int i=0;i<4;i++){
      #pragma unroll
      for (int r=0;r<4;r++){
        int row = row0 + wr + i*16 + lhi*4 + r;
        if (row < M) C[(size_t)row*EDIM + col] = f2h(acc[i][j][r] + bv);
      }
    }
  }
}

// ---------------- fused attention: swapped QK^T; ALL scores first, ONE exact
// softmax (no online rescaling), then per-tile P/PV.  R19 staging/PV forms.
__global__ __launch_bounds__(512, 2) void attn_kernel(
    const ushort* __restrict__ rfeat,   // [NRB][512]
    const ushort* __restrict__ dfeat,   // [NDB][512]
    const ushort* __restrict__ dflt,    // [64][NDB]
    ushort* __restrict__ accbuf,        // [SPLIT][NRB][64] fp16 partials
    float* __restrict__ mlbuf)          // [SPLIT][NRB][4]
{
  __shared__ ushort DF[DPB*512];  // 96 KB: whole split's domain tile, swizzled
  __shared__ ushort PT[8][16*32]; // per-wave P scratch, swizzled (8KB)

  const int tid  = threadIdx.x;
  const int wave = tid >> 6;
  const int lane = tid & 63;
  const int l15  = lane & 15;
  const int lhi  = lane >> 4;
  const int wrow = blockIdx.x*128 + wave*16;
  const int by   = blockIdx.y;           // split index
  const int dbase = by * DPB;

  constexpr float CL = 0.25f * 1.4426950408889634f;
  constexpr float CH = 0.08838834764831845f;

  char* DFb = (char*)DF;
  char* PTb = (char*)PT[wave];

  // stage the whole 96-domain tile once (12 chunks/thread, per-row XOR swizzle)
  #pragma unroll
  for (int c=0;c<12;c++){
    int id = tid + c*512;
    int dom = id >> 6;
    h8 v = *(const h8*)(dfeat + (size_t)(dbase+dom)*EDIM + (id&63)*8);
    *(h8*)(DFb + ((id*16) ^ ((dom&7)<<4))) = v;
  }

  // Q fragments in registers (qrow = wrow + l15)
  h8 q[16];
  {
    const ushort* qr = rfeat + (size_t)(wrow + l15)*EDIM + lhi*8;
    #pragma unroll
    for (int c=0;c<16;c++) q[c] = *(const h8*)(qr + c*32);
  }

  f4 acc[4] = {};
  const int sb = (lane & 48) + ((lane >> 4) << 2);
  (void)sb;

  __syncthreads();   // DF ready; the ONLY block barrier

  // Phase 1: ALL scores for the block's 96 domains (144 independent MFMAs)
  f4 SL[TILES][2] = {}, SC[TILES][2] = {}, SO[TILES][2] = {};
  #pragma unroll
  for (int t=0; t<TILES; ++t){
    #pragma unroll
    for (int ct=0; ct<2; ++ct){
      const int dom = t*32 + ct*16 + l15;
      const int swz = (dom&7)<<4;
      const int base = dom*1024 + lhi*16;
      #pragma unroll
      for (int c=0;c<8;c++){
        h8 b = *(const h8*)(DFb + ((base + c*64) ^ swz));
        SL[t][ct] = MFMA(b, q[c], SL[t][ct]);
      }
      #pragma unroll
      for (int c=8;c<12;c++){
        h8 b = *(const h8*)(DFb + ((base + c*64) ^ swz));
        SC[t][ct] = MFMA(b, q[c], SC[t][ct]);
      }
      #pragma unroll
      for (int c=12;c<16;c++){
        h8 b = *(const h8*)(DFb + ((base + c*64) ^ swz));
        SO[t][ct] = MFMA(b, q[c], SO[t][ct]);
      }
    }
  }

  // Phase 2: one exact row-max over all 96 domains (24 lane-local + 2 shuffles)
  float lm = -1e30f;
  #pragma unroll
  for (int t=0; t<TILES; ++t){
    #pragma unroll
    for (int ct=0; ct<2; ++ct){
      lm = fmaxf(lm, fmaxf(fmaxf(SL[t][ct][0],SL[t][ct][1]),
                           fmaxf(SL[t][ct][2],SL[t][ct][3])));
    }
  }
  lm *= CL;
  lm = fmaxf(lm, __shfl_xor(lm, 16, 64));
  float m = fmaxf(lm, __shfl_xor(lm, 32, 64));   // final row max, no rescaling ever
  float lsum = 0.f, offa = 0.f;

  // Phase 3: per tile, p/gates -> PT -> PV (no acc rescale)
  #pragma unroll
  for (int t=0; t<TILES; ++t){
    const int d0 = dbase + t*32;

    us4 w0, w1;
    #pragma unroll
    for (int r=0;r<4;r++){
      float p0 = __builtin_amdgcn_exp2f(SL[t][0][r]*CL - m);
      float p1 = __builtin_amdgcn_exp2f(SL[t][1][r]*CL - m);
      lsum += p0 + p1;
      float c0 = tanh_fast(SC[t][0][r]*CH)*1.8f;
      float c1 = tanh_fast(SC[t][1][r]*CH)*1.8f;
      float o0 = tanh_fast(SO[t][0][r]*CH);
      float o1 = tanh_fast(SO[t][1][r]*CH);
      offa += p0*o0 + p1*o1;
      w0[r] = f2h(p0*c0);
      w1[r] = f2h(p1*c1);
    }
    {
      const int wbase = l15*64;
      const int xs = (l15&3)<<4;
      *(us4*)(PTb + ((wbase + lhi*8) ^ xs))      = w0;
      *(us4*)(PTb + ((wbase + 32 + lhi*8) ^ xs)) = w1;
    }

    // pin order: PT writes before PV PT-read (same-wave DS pipe is in-order)
    __builtin_amdgcn_sched_barrier(0);

    {
      h8 pa = *(const h8*)(PTb + ((l15*64 + lhi*16) ^ ((l15&3)<<4)));
      #pragma unroll
      for (int nt=0; nt<4; nt++){
        int n = nt*16 + l15;
        h8 vb = *(const h8*)(dflt + (size_t)n*NDB + d0 + lhi*8);
        acc[nt] = MFMA(pa, vb, acc[nt]);
      }
    }

    // pin order: PV PT-read stays before next tile's PT writes
    __builtin_amdgcn_sched_barrier(0);
  }

  // epilogue: reduce l/off across lhi, store fp16 partials
  float ls = lsum, oa = offa;
  ls += __shfl_xor(ls, 16, 64); ls += __shfl_xor(ls, 32, 64);
  oa += __shfl_xor(oa, 16, 64); oa += __shfl_xor(oa, 32, 64);

  #pragma unroll
  for (int r=0;r<4;r++){
    int row = wrow + lhi*4 + r;
    size_t base = ((size_t)by*NRB + row)*64;
    #pragma unroll
    for (int nt=0; nt<4; nt++){
      accbuf[base + nt*16 + l15] = f2h(acc[nt][r]);
    }
  }
  if (lane < 16){
    size_t mo = ((size_t)by*NRB + wrow + l15)*4;
    mlbuf[mo+0] = m;
    mlbuf[mo+1] = ls;
    mlbuf[mo+2] = oa;
  }
}

// ---------------- combine partials (fp16 accbuf), 16 rows/block = 864 blocks
#define CROWS 16
__global__ __launch_bounds__(256) void combine_kernel(
    const ushort* __restrict__ accbuf,
    const float* __restrict__ mlbuf,
    float* __restrict__ out)
{
  __shared__ float wS[CROWS][SPLIT+1];
  __shared__ float c0S[CROWS], iTS[CROWS];
  const int rb = blockIdx.x;
  const int tid = threadIdx.x;

  if (tid < CROWS){
    int row = rb*CROWS + tid;
    float M = -1e30f;
    float m[SPLIT], l[SPLIT], o[SPLIT];
    #pragma unroll
    for (int s=0;s<SPLIT;s++){
      size_t off = ((size_t)s*NRB + row)*4;
      m[s]=mlbuf[off]; l[s]=mlbuf[off+1]; o[s]=mlbuf[off+2];
      M = fmaxf(M, m[s]);
    }
    float T=0.f, C=0.f;
    #pragma unroll
    for (int s=0;s<SPLIT;s++){
      float w = __builtin_amdgcn_exp2f(m[s]-M);
      wS[tid][s]=w; T += l[s]*w; C += o[s]*w;
    }
    c0S[tid]=C; iTS[tid]=1.0f/T;
  }
  __syncthreads();

  const int row_l = tid>>4;         // 0..15
  const int cb = (tid&15)*4;        // 0..60
  const int row = rb*CROWS + row_l;
  float res[4] = {};
  #pragma unroll
  for (int s=0;s<SPLIT;s++){
    float w = wS[row_l][s];
    hh4 v = *(const hh4*)(accbuf + ((size_t)s*NRB + row)*64 + cb);
    #pragma unroll
    for (int j=0;j<4;j++) res[j] += (float)v[j]*w;
  }
  float C = c0S[row_l], iT = iTS[row_l];
  #pragma unroll
  for (int j=0;j<4;j++) out[(size_t)row*64 + cb + j] = (res[j]+C)*iT;
}

extern "C" void kernel_launch(void* const* d_in, const int* in_sizes, int n_in,
                              void* d_out, int out_size, void* d_ws, size_t ws_size,
                              hipStream_t stream) {
  const float* pooled = (const float*)d_in[0];
  const float* rlat   = (const float*)d_in[1];
  const float* dlat   = (const float*)d_in[2];
  const float* rpos   = (const float*)d_in[3];
  const float* dpos   = (const float*)d_in[4];
  const float* Wrp    = (const float*)d_in[5];
  const float* brp    = (const float*)d_in[6];
  const float* Wdp    = (const float*)d_in[7];
  const float* bdp    = (const float*)d_in[8];
  const float* Wrc    = (const float*)d_in[9];
  const float* brc    = (const float*)d_in[10];
  const float* Wdc    = (const float*)d_in[11];
  const float* bdc    = (const float*)d_in[12];
  const float* Wro    = (const float*)d_in[13];
  const float* bro    = (const float*)d_in[14];
  const float* Wdo2   = (const float*)d_in[15];
  const float* bdo2   = (const float*)d_in[16];

  char* ws = (char*)d_ws;
  size_t off = 0;
  ushort* rb    = (ushort*)(ws + off); off += (size_t)NRB*EDIM*2;
  ushort* db    = (ushort*)(ws + off); off += (size_t)NDB*EDIM*2;
  ushort* Wr_t  = (ushort*)(ws + off); off += (size_t)512*512*2;
  ushort* Wd_t  = (ushort*)(ws + off); off += (size_t)512*512*2;
  float*  br_c  = (float*)(ws + off);  off += 512*4;
  float*  bd_c  = (float*)(ws + off);  off += 512*4;
  ushort* rfeat = (ushort*)(ws + off); off += (size_t)NRB*EDIM*2;
  ushort* dfeat = (ushort*)(ws + off); off += (size_t)NDB*EDIM*2;
  ushort* dflt  = (ushort*)(ws + off); off += (size_t)64*NDB*2;
  ushort* accb  = (ushort*)(ws + off); off += (size_t)SPLIT*NRB*64*2;
  float*  mlb   = (float*)(ws + off);  off += (size_t)SPLIT*NRB*4*4;

  prep_kernel<<<2048, 256, 0, stream>>>(pooled, rlat, dlat, rpos, dpos,
      Wrp, brp, Wdp, bdp, Wrc, brc, Wdc, bdc, Wro, bro, Wdo2, bdo2,
      rb, db, Wr_t, Wd_t, br_c, bd_c, dflt);

  gemm_feats<<<dim3(122,4), 256, 0, stream>>>(rb, Wr_t, br_c, rfeat,
                                              db, Wd_t, bd_c, dfeat);

  attn_kernel<<<dim3(108, SPLIT), 512, 0, stream>>>(rfeat, dfeat, dflt, accb, mlb);
  combine_kernel<<<NRB/CROWS, 256, 0, stream>>>(accb, mlb, (float*)d_out);
}

// Round 22
// 132.685 us; speedup vs baseline: 1.0547x; 1.0345x over previous
//
#include <hip/hip_runtime.h>
#include <stdint.h>

#define NRB 13824
#define NDB 1728
#define EDIM 512
#define SPLIT 18
#define DPB (NDB/SPLIT)   // 96 domains per block
#define TILES (DPB/32)    // 3

typedef __attribute__((ext_vector_type(8))) _Float16 h8;
typedef __attribute__((ext_vector_type(4))) _Float16 hh4;
typedef __attribute__((ext_vector_type(4))) float f4;
typedef __attribute__((ext_vector_type(4))) unsigned short us4;

typedef __attribute__((address_space(3))) void lds_void;
typedef const __attribute__((address_space(1))) void gbl_void;

#define MFMA(a,b,c) __builtin_amdgcn_mfma_f32_16x16x32_f16(a,b,c,0,0,0)

static __device__ __forceinline__ ushort f2h(float f){
  union { _Float16 h; ushort u; } cv;
  cv.h = (_Float16)f;
  return cv.u;
}

static __device__ __forceinline__ float tanh_fast(float x){
  float ax = __builtin_fabsf(x);
  float t = __builtin_amdgcn_exp2f(ax * -2.8853900817779268f); // exp(-2ax)
  float r = (1.0f - t) * __builtin_amdgcn_rcpf(1.0f + t);
  return __builtin_copysignf(r, x);
}

// ---------------- prep (bases->fp16, weights concat+transpose, V transpose)
__global__ void prep_kernel(
    const float* __restrict__ pooled,
    const float* __restrict__ rlat, const float* __restrict__ dlat,
    const float* __restrict__ rpos, const float* __restrict__ dpos,
    const float* __restrict__ Wrp, const float* __restrict__ brp,
    const float* __restrict__ Wdp, const float* __restrict__ bdp,
    const float* __restrict__ Wrc, const float* __restrict__ brc,
    const float* __restrict__ Wdc, const float* __restrict__ bdc,
    const float* __restrict__ Wro, const float* __restrict__ bro,
    const float* __restrict__ Wdo2, const float* __restrict__ bdo2,
    ushort* __restrict__ rb, ushort* __restrict__ db,
    ushort* __restrict__ Wr_t, ushort* __restrict__ Wd_t,
    float* __restrict__ br_c, float* __restrict__ bd_c,
    ushort* __restrict__ dflt)
{
  const int NRE = NRB*EDIM, NDE = NDB*EDIM;
  int i0 = blockIdx.x*blockDim.x + threadIdx.x;
  int stride = gridDim.x*blockDim.x;
  for (int i=i0; i<NRE; i+=stride) rb[i] = f2h(rlat[i]+rpos[i]);
  for (int i=i0; i<NDE; i+=stride) db[i] = f2h(dlat[i]+dpos[i]);
  for (int i=i0; i<512*512; i+=stride){
    int n = i>>9, k = i&511;
    float vr = (n<256) ? Wrp[k*256+n] : ((n<384) ? Wrc[k*128+(n-256)] : Wro[k*128+(n-384)]);
    float vd = (n<256) ? Wdp[k*256+n] : ((n<384) ? Wdc[k*128+(n-256)] : Wdo2[k*128+(n-384)]);
    Wr_t[i] = f2h(vr); Wd_t[i] = f2h(vd);
  }
  for (int i=i0; i<512; i+=stride){
    br_c[i] = (i<256) ? brp[i] : ((i<384) ? brc[i-256] : bro[i-384]);
    bd_c[i] = (i<256) ? bdp[i] : ((i<384) ? bdc[i-256] : bdo2[i-384]);
  }
  for (int i=i0; i<64*NDB; i+=stride){
    int c = i/NDB, d = i - c*NDB;
    dflt[i] = f2h(pooled[d*64+c]);
  }
}

// ---------------- feats GEMM (fp16 A), both r- and d-side in one launch
__global__ __launch_bounds__(256) void gemm_feats(
    const ushort* __restrict__ Ar, const ushort* __restrict__ Btr,
    const float* __restrict__ biasr, ushort* __restrict__ Cr,
    const ushort* __restrict__ Ad, const ushort* __restrict__ Btd,
    const float* __restrict__ biasd, ushort* __restrict__ Cd)
{
  const ushort* A;  const ushort* Bt; const float* bias; ushort* C; int M; int bx;
  if ((int)blockIdx.x < 108){ A=Ar; Bt=Btr; bias=biasr; C=Cr; M=NRB; bx=blockIdx.x; }
  else                      { A=Ad; Bt=Btd; bias=biasd; C=Cd; M=NDB; bx=blockIdx.x-108; }

  __shared__ ushort As[128*32];
  __shared__ ushort Bs[128*32];
  const int tid = threadIdx.x;
  const int lane = tid & 63;
  const int wave = tid >> 6;
  const int l15 = lane & 15;
  const int lhi = lane >> 4;
  const int row0 = bx * 128;
  const int col0 = blockIdx.y * 128;
  const int wr = (wave>>1)*64;
  const int wc = (wave&1)*64;

  f4 acc[4][4] = {};
  char* Ab = (char*)As; char* Bb = (char*)Bs;

  for (int k0=0; k0<EDIM; k0+=32){
    __syncthreads();
    #pragma unroll
    for (int c=0;c<2;c++){
      int L = (tid + c*256)*16;
      int r = L>>6;
      int kb = L&63;
      int kbs = kb ^ ((r&3)<<4);
      int ra = row0 + r; if (ra > M-1) ra = M-1;
      const ushort* srcA = A + (size_t)ra*EDIM + k0 + (kbs>>1);
      const ushort* srcB = Bt + (size_t)(col0+r)*EDIM + k0 + (kbs>>1);
      __builtin_amdgcn_global_load_lds((gbl_void*)srcA, (lds_void*)(Ab + L), 16, 0, 0);
      __builtin_amdgcn_global_load_lds((gbl_void*)srcB, (lds_void*)(Bb + L), 16, 0, 0);
    }
    __syncthreads();
    h8 af[4], bf[4];
    #pragma unroll
    for (int i=0;i<4;i++){
      int rowa = wr + i*16 + l15;
      af[i] = *(const h8*)(Ab + (((rowa*64) + lhi*16) ^ ((rowa&3)<<4)));
      int rowb = wc + i*16 + l15;
      bf[i] = *(const h8*)(Bb + (((rowb*64) + lhi*16) ^ ((rowb&3)<<4)));
    }
    #pragma unroll
    for (int i=0;i<4;i++){
      #pragma unroll
      for (int j=0;j<4;j++){
        acc[i][j] = MFMA(af[i], bf[j], acc[i][j]);
      }
    }
  }

  #pragma unroll
  for (int j=0;j<4;j++){
    int col = col0 + wc + j*16 + l15;
    float bv = bias[col];
    #pragma unroll
    for (int i=0;i<4;i++){
      #pragma unroll
      for (int r=0;r<4;r++){
        int row = row0 + wr + i*16 + lhi*4 + r;
        if (row < M) C[(size_t)row*EDIM + col] = f2h(acc[i][j][r] + bv);
      }
    }
  }
}

// ---------------- fused attention: swapped-operand QK^T, lane-local softmax (R17 proven)
__global__ __launch_bounds__(512, 2) void attn_kernel(
    const ushort* __restrict__ rfeat,   // [NRB][512]
    const ushort* __restrict__ dfeat,   // [NDB][512]
    const ushort* __restrict__ dflt,    // [64][NDB]
    ushort* __restrict__ accbuf,        // [SPLIT][NRB][64] fp16 partials
    float* __restrict__ mlbuf)          // [SPLIT][NRB][4]
{
  __shared__ ushort DF[DPB*512];  // 96 KB: whole split's domain tile, swizzled
  __shared__ ushort PT[8][16*32]; // per-wave P scratch, swizzled (8KB)

  const int tid  = threadIdx.x;
  const int wave = tid >> 6;
  const int lane = tid & 63;
  const int l15  = lane & 15;
  const int lhi  = lane >> 4;
  const int wrow = blockIdx.x*128 + wave*16;
  const int by   = blockIdx.y;           // split index
  const int dbase = by * DPB;

  constexpr float CL = 0.25f * 1.4426950408889634f;
  constexpr float CH = 0.08838834764831845f;

  char* DFb = (char*)DF;
  char* PTb = (char*)PT[wave];

  // stage the whole 96-domain tile once (12 chunks/thread, per-row XOR swizzle)
  #pragma unroll
  for (int c=0;c<12;c++){
    int id = tid + c*512;
    int dom = id >> 6;
    h8 v = *(const h8*)(dfeat + (size_t)(dbase+dom)*EDIM + (id&63)*8);
    *(h8*)(DFb + ((id*16) ^ ((dom&7)<<4))) = v;
  }

  // Q fragments in registers (qrow = wrow + l15)
  h8 q[16];
  {
    const ushort* qr = rfeat + (size_t)(wrow + l15)*EDIM + lhi*8;
    #pragma unroll
    for (int c=0;c<16;c++) q[c] = *(const h8*)(qr + c*32);
  }

  f4 acc[4] = {};
  float m = -1e30f, lsum = 0.f, offa = 0.f;
  const int sb = (lane & 48) + ((lane >> 4) << 2);  // gather src base: lhi*16 + lhi*4

  __syncthreads();   // DF ready; the ONLY block barrier

  for (int t=0; t<TILES; ++t){
    const int d0 = dbase + t*32;
    const int dloc = t*32;

    // swapped QK^T: A = domain fragment (dom = dloc+ct*16+l15), B = q
    f4 SL[2] = {}, SC[2] = {}, SO[2] = {};
    #pragma unroll
    for (int ct=0; ct<2; ++ct){
      const int dom = dloc + ct*16 + l15;
      const int swz = (dom&7)<<4;
      const int base = dom*1024 + lhi*16;
      #pragma unroll
      for (int c=0;c<8;c++){
        h8 b = *(const h8*)(DFb + ((base + c*64) ^ swz));
        SL[ct] = MFMA(b, q[c], SL[ct]);
      }
      #pragma unroll
      for (int c=8;c<12;c++){
        h8 b = *(const h8*)(DFb + ((base + c*64) ^ swz));
        SC[ct] = MFMA(b, q[c], SC[ct]);
      }
      #pragma unroll
      for (int c=12;c<16;c++){
        h8 b = *(const h8*)(DFb + ((base + c*64) ^ swz));
        SO[ct] = MFMA(b, q[c], SO[ct]);
      }
    }

    // lane-local softmax for qrow = l15 (8 doms per lane, spread over lhi)
    float lm = fmaxf(
        fmaxf(fmaxf(SL[0][0],SL[0][1]), fmaxf(SL[0][2],SL[0][3])),
        fmaxf(fmaxf(SL[1][0],SL[1][1]), fmaxf(SL[1][2],SL[1][3]))) * CL;
    lm = fmaxf(lm, __shfl_xor(lm, 16, 64));
    lm = fmaxf(lm, __shfl_xor(lm, 32, 64));   // exact row max, uniform across lhi
    float mn = fmaxf(m, lm);
    float al = __builtin_amdgcn_exp2f(m - mn);
    m = mn;
    lsum *= al; offa *= al;

    us4 w0, w1;
    #pragma unroll
    for (int r=0;r<4;r++){
      float p0 = __builtin_amdgcn_exp2f(SL[0][r]*CL - mn);
      float p1 = __builtin_amdgcn_exp2f(SL[1][r]*CL - mn);
      lsum += p0 + p1;
      float c0 = tanh_fast(SC[0][r]*CH)*1.8f;
      float c1 = tanh_fast(SC[1][r]*CH)*1.8f;
      float o0 = tanh_fast(SO[0][r]*CH);
      float o1 = tanh_fast(SO[1][r]*CH);
      offa += p0*o0 + p1*o1;
      w0[r] = f2h(p0*c0);
      w1[r] = f2h(p1*c1);
    }
    // PT write: row qrow=l15, doms ct*16+lhi*4..+4 as b64, swizzle ^((l15&3)<<4)
    {
      const int wbase = l15*64;
      const int xs = (l15&3)<<4;
      *(us4*)(PTb + ((wbase + lhi*8) ^ xs))      = w0;
      *(us4*)(PTb + ((wbase + 32 + lhi*8) ^ xs)) = w1;
    }

    // pin order: PT writes before PV PT-read (same-wave DS pipe is in-order)
    __builtin_amdgcn_sched_barrier(0);

    // PV: gather al for rows lhi*4+r, rescale acc, then MFMA
    {
      float alr[4];
      #pragma unroll
      for (int r=0;r<4;r++) alr[r] = __shfl(al, sb + r, 64);
      #pragma unroll
      for (int nt=0; nt<4; nt++){
        acc[nt][0]*=alr[0]; acc[nt][1]*=alr[1];
        acc[nt][2]*=alr[2]; acc[nt][3]*=alr[3];
      }
      h8 pa = *(const h8*)(PTb + ((l15*64 + lhi*16) ^ ((l15&3)<<4)));
      #pragma unroll
      for (int nt=0; nt<4; nt++){
        int n = nt*16 + l15;
        h8 vb = *(const h8*)(dflt + (size_t)n*NDB + d0 + lhi*8);
        acc[nt] = MFMA(pa, vb, acc[nt]);
      }
    }

    // pin order: PV PT-read stays before next iteration's PT writes
    __builtin_amdgcn_sched_barrier(0);
  }

  // epilogue: reduce l/off across lhi, store fp16 partials
  float ls = lsum, oa = offa;
  ls += __shfl_xor(ls, 16, 64); ls += __shfl_xor(ls, 32, 64);
  oa += __shfl_xor(oa, 16, 64); oa += __shfl_xor(oa, 32, 64);

  #pragma unroll
  for (int r=0;r<4;r++){
    int row = wrow + lhi*4 + r;
    size_t base = ((size_t)by*NRB + row)*64;
    #pragma unroll
    for (int nt=0; nt<4; nt++){
      accbuf[base + nt*16 + l15] = f2h(acc[nt][r]);
    }
  }
  if (lane < 16){
    size_t mo = ((size_t)by*NRB + wrow + l15)*4;
    mlbuf[mo+0] = m;
    mlbuf[mo+1] = ls;
    mlbuf[mo+2] = oa;
  }
}

// ---------------- combine partials (fp16 accbuf), 16 rows/block = 864 blocks
#define CROWS 16
__global__ __launch_bounds__(256) void combine_kernel(
    const ushort* __restrict__ accbuf,
    const float* __restrict__ mlbuf,
    float* __restrict__ out)
{
  __shared__ float wS[CROWS][SPLIT+1];
  __shared__ float c0S[CROWS], iTS[CROWS];
  const int rb = blockIdx.x;
  const int tid = threadIdx.x;

  if (tid < CROWS){
    int row = rb*CROWS + tid;
    float M = -1e30f;
    float m[SPLIT], l[SPLIT], o[SPLIT];
    #pragma unroll
    for (int s=0;s<SPLIT;s++){
      size_t off = ((size_t)s*NRB + row)*4;
      m[s]=mlbuf[off]; l[s]=mlbuf[off+1]; o[s]=mlbuf[off+2];
      M = fmaxf(M, m[s]);
    }
    float T=0.f, C=0.f;
    #pragma unroll
    for (int s=0;s<SPLIT;s++){
      float w = __builtin_amdgcn_exp2f(m[s]-M);
      wS[tid][s]=w; T += l[s]*w; C += o[s]*w;
    }
    c0S[tid]=C; iTS[tid]=1.0f/T;
  }
  __syncthreads();

  const int row_l = tid>>4;         // 0..15
  const int cb = (tid&15)*4;        // 0..60
  const int row = rb*CROWS + row_l;
  float res[4] = {};
  #pragma unroll
  for (int s=0;s<SPLIT;s++){
    float w = wS[row_l][s];
    hh4 v = *(const hh4*)(accbuf + ((size_t)s*NRB + row)*64 + cb);
    #pragma unroll
    for (int j=0;j<4;j++) res[j] += (float)v[j]*w;
  }
  float C = c0S[row_l], iT = iTS[row_l];
  #pragma unroll
  for (int j=0;j<4;j++) out[(size_t)row*64 + cb + j] = (res[j]+C)*iT;
}

extern "C" void kernel_launch(void* const* d_in, const int* in_sizes, int n_in,
                              void* d_out, int out_size, void* d_ws, size_t ws_size,
                              hipStream_t stream) {
  const float* pooled = (const float*)d_in[0];
  const float* rlat   = (const float*)d_in[1];
  const float* dlat   = (const float*)d_in[2];
  const float* rpos   = (const float*)d_in[3];
  const float* dpos   = (const float*)d_in[4];
  const float* Wrp    = (const float*)d_in[5];
  const float* brp    = (const float*)d_in[6];
  const float* Wdp    = (const float*)d_in[7];
  const float* bdp    = (const float*)d_in[8];
  const float* Wrc    = (const float*)d_in[9];
  const float* brc    = (const float*)d_in[10];
  const float* Wdc    = (const float*)d_in[11];
  const float* bdc    = (const float*)d_in[12];
  const float* Wro    = (const float*)d_in[13];
  const float* bro    = (const float*)d_in[14];
  const float* Wdo2   = (const float*)d_in[15];
  const float* bdo2   = (const float*)d_in[16];

  char* ws = (char*)d_ws;
  size_t off = 0;
  ushort* rb    = (ushort*)(ws + off); off += (size_t)NRB*EDIM*2;
  ushort* db    = (ushort*)(ws + off); off += (size_t)NDB*EDIM*2;
  ushort* Wr_t  = (ushort*)(ws + off); off += (size_t)512*512*2;
  ushort* Wd_t  = (ushort*)(ws + off); off += (size_t)512*512*2;
  float*  br_c  = (float*)(ws + off);  off += 512*4;
  float*  bd_c  = (float*)(ws + off);  off += 512*4;
  ushort* rfeat = (ushort*)(ws + off); off += (size_t)NRB*EDIM*2;
  ushort* dfeat = (ushort*)(ws + off); off += (size_t)NDB*EDIM*2;
  ushort* dflt  = (ushort*)(ws + off); off += (size_t)64*NDB*2;
  ushort* accb  = (ushort*)(ws + off); off += (size_t)SPLIT*NRB*64*2;
  float*  mlb   = (float*)(ws + off);  off += (size_t)SPLIT*NRB*4*4;

  prep_kernel<<<2048, 256, 0, stream>>>(pooled, rlat, dlat, rpos, dpos,
      Wrp, brp, Wdp, bdp, Wrc, brc, Wdc, bdc, Wro, bro, Wdo2, bdo2,
      rb, db, Wr_t, Wd_t, br_c, bd_c, dflt);

  gemm_feats<<<dim3(122,4), 256, 0, stream>>>(rb, Wr_t, br_c, rfeat,
                                              db, Wd_t, bd_c, dfeat);

  attn_kernel<<<dim3(108, SPLIT), 512, 0, stream>>>(rfeat, dfeat, dflt, accb, mlb);
  combine_kernel<<<NRB/CROWS, 256, 0, stream>>>(accb, mlb, (float*)d_out);
}

// Round 23
// 132.674 us; speedup vs baseline: 1.0548x; 1.0001x over previous
//
#include <hip/hip_runtime.h>
#include <stdint.h>

#define NRB 13824
#define NDB 1728
#define EDIM 512
#define SPLIT 18
#define DPB (NDB/SPLIT)   // 96 domains per block
#define TILES (DPB/32)    // 3
#define NBX 108
#define NWG (NBX*SPLIT)   // 1944 = 8 * 243
#define CPX (NWG/8)       // 243 blocks per XCD chunk

typedef __attribute__((ext_vector_type(8))) _Float16 h8;
typedef __attribute__((ext_vector_type(4))) _Float16 hh4;
typedef __attribute__((ext_vector_type(4))) float f4;
typedef __attribute__((ext_vector_type(4))) unsigned short us4;

typedef __attribute__((address_space(3))) void lds_void;
typedef const __attribute__((address_space(1))) void gbl_void;

#define MFMA(a,b,c) __builtin_amdgcn_mfma_f32_16x16x32_f16(a,b,c,0,0,0)

static __device__ __forceinline__ ushort f2h(float f){
  union { _Float16 h; ushort u; } cv;
  cv.h = (_Float16)f;
  return cv.u;
}

static __device__ __forceinline__ float tanh_fast(float x){
  float ax = __builtin_fabsf(x);
  float t = __builtin_amdgcn_exp2f(ax * -2.8853900817779268f); // exp(-2ax)
  float r = (1.0f - t) * __builtin_amdgcn_rcpf(1.0f + t);
  return __builtin_copysignf(r, x);
}

// ---------------- prep (bases->fp16, weights concat+transpose, V transpose)
__global__ void prep_kernel(
    const float* __restrict__ pooled,
    const float* __restrict__ rlat, const float* __restrict__ dlat,
    const float* __restrict__ rpos, const float* __restrict__ dpos,
    const float* __restrict__ Wrp, const float* __restrict__ brp,
    const float* __restrict__ Wdp, const float* __restrict__ bdp,
    const float* __restrict__ Wrc, const float* __restrict__ brc,
    const float* __restrict__ Wdc, const float* __restrict__ bdc,
    const float* __restrict__ Wro, const float* __restrict__ bro,
    const float* __restrict__ Wdo2, const float* __restrict__ bdo2,
    ushort* __restrict__ rb, ushort* __restrict__ db,
    ushort* __restrict__ Wr_t, ushort* __restrict__ Wd_t,
    float* __restrict__ br_c, float* __restrict__ bd_c,
    ushort* __restrict__ dflt)
{
  const int NRE = NRB*EDIM, NDE = NDB*EDIM;
  int i0 = blockIdx.x*blockDim.x + threadIdx.x;
  int stride = gridDim.x*blockDim.x;
  for (int i=i0; i<NRE; i+=stride) rb[i] = f2h(rlat[i]+rpos[i]);
  for (int i=i0; i<NDE; i+=stride) db[i] = f2h(dlat[i]+dpos[i]);
  for (int i=i0; i<512*512; i+=stride){
    int n = i>>9, k = i&511;
    float vr = (n<256) ? Wrp[k*256+n] : ((n<384) ? Wrc[k*128+(n-256)] : Wro[k*128+(n-384)]);
    float vd = (n<256) ? Wdp[k*256+n] : ((n<384) ? Wdc[k*128+(n-256)] : Wdo2[k*128+(n-384)]);
    Wr_t[i] = f2h(vr); Wd_t[i] = f2h(vd);
  }
  for (int i=i0; i<512; i+=stride){
    br_c[i] = (i<256) ? brp[i] : ((i<384) ? brc[i-256] : bro[i-384]);
    bd_c[i] = (i<256) ? bdp[i] : ((i<384) ? bdc[i-256] : bdo2[i-384]);
  }
  for (int i=i0; i<64*NDB; i+=stride){
    int c = i/NDB, d = i - c*NDB;
    dflt[i] = f2h(pooled[d*64+c]);
  }
}

// ---------------- feats GEMM (fp16 A), both r- and d-side in one launch
__global__ __launch_bounds__(256) void gemm_feats(
    const ushort* __restrict__ Ar, const ushort* __restrict__ Btr,
    const float* __restrict__ biasr, ushort* __restrict__ Cr,
    const ushort* __restrict__ Ad, const ushort* __restrict__ Btd,
    const float* __restrict__ biasd, ushort* __restrict__ Cd)
{
  const ushort* A;  const ushort* Bt; const float* bias; ushort* C; int M; int bx;
  if ((int)blockIdx.x < 108){ A=Ar; Bt=Btr; bias=biasr; C=Cr; M=NRB; bx=blockIdx.x; }
  else                      { A=Ad; Bt=Btd; bias=biasd; C=Cd; M=NDB; bx=blockIdx.x-108; }

  __shared__ ushort As[128*32];
  __shared__ ushort Bs[128*32];
  const int tid = threadIdx.x;
  const int lane = tid & 63;
  const int wave = tid >> 6;
  const int l15 = lane & 15;
  const int lhi = lane >> 4;
  const int row0 = bx * 128;
  const int col0 = blockIdx.y * 128;
  const int wr = (wave>>1)*64;
  const int wc = (wave&1)*64;

  f4 acc[4][4] = {};
  char* Ab = (char*)As; char* Bb = (char*)Bs;

  for (int k0=0; k0<EDIM; k0+=32){
    __syncthreads();
    #pragma unroll
    for (int c=0;c<2;c++){
      int L = (tid + c*256)*16;
      int r = L>>6;
      int kb = L&63;
      int kbs = kb ^ ((r&3)<<4);
      int ra = row0 + r; if (ra > M-1) ra = M-1;
      const ushort* srcA = A + (size_t)ra*EDIM + k0 + (kbs>>1);
      const ushort* srcB = Bt + (size_t)(col0+r)*EDIM + k0 + (kbs>>1);
      __builtin_amdgcn_global_load_lds((gbl_void*)srcA, (lds_void*)(Ab + L), 16, 0, 0);
      __builtin_amdgcn_global_load_lds((gbl_void*)srcB, (lds_void*)(Bb + L), 16, 0, 0);
    }
    __syncthreads();
    h8 af[4], bf[4];
    #pragma unroll
    for (int i=0;i<4;i++){
      int rowa = wr + i*16 + l15;
      af[i] = *(const h8*)(Ab + (((rowa*64) + lhi*16) ^ ((rowa&3)<<4)));
      int rowb = wc + i*16 + l15;
      bf[i] = *(const h8*)(Bb + (((rowb*64) + lhi*16) ^ ((rowb&3)<<4)));
    }
    #pragma unroll
    for (int i=0;i<4;i++){
      #pragma unroll
      for (int j=0;j<4;j++){
        acc[i][j] = MFMA(af[i], bf[j], acc[i][j]);
      }
    }
  }

  #pragma unroll
  for (int j=0;j<4;j++){
    int col = col0 + wc + j*16 + l15;
    float bv = bias[col];
    #pragma unroll
    for (int i=0;i<4;i++){
      #pragma unroll
      for (int r=0;r<4;r++){
        int row = row0 + wr + i*16 + lhi*4 + r;
        if (row < M) C[(size_t)row*EDIM + col] = f2h(acc[i][j][r] + bv);
      }
    }
  }
}

// ---------------- fused attention: swapped-operand QK^T, lane-local softmax
// grid: 1D NWG with bijective XCD-chunk swizzle (keeps all splits of the same
// Q-row range on one XCD so rfeat is L2-served)
__global__ __launch_bounds__(512, 2) void attn_kernel(
    const ushort* __restrict__ rfeat,   // [NRB][512]
    const ushort* __restrict__ dfeat,   // [NDB][512]
    const ushort* __restrict__ dflt,    // [64][NDB]
    ushort* __restrict__ accbuf,        // [SPLIT][NRB][64] fp16 partials
    float* __restrict__ mlbuf)          // [SPLIT][NRB][4]
{
  __shared__ ushort DF[DPB*512];  // 96 KB: whole split's domain tile, swizzled
  __shared__ ushort PT[8][16*32]; // per-wave P scratch, swizzled (8KB)

  // XCD-aware bijective remap: consecutive hardware wgids round-robin XCDs;
  // chunk c gets ids [c*CPX, (c+1)*CPX) -> x-major decode keeps same-x splits
  // co-resident on one XCD. NWG % 8 == 0 so this is exactly bijective.
  const int lin = blockIdx.x;
  const int id  = (lin & 7)*CPX + (lin >> 3);
  const int bx  = id / SPLIT;
  const int by  = id - bx*SPLIT;

  const int tid  = threadIdx.x;
  const int wave = tid >> 6;
  const int lane = tid & 63;
  const int l15  = lane & 15;
  const int lhi  = lane >> 4;
  const int wrow = bx*128 + wave*16;
  const int dbase = by * DPB;

  constexpr float CL = 0.25f * 1.4426950408889634f;
  constexpr float CH = 0.08838834764831845f;

  char* DFb = (char*)DF;
  char* PTb = (char*)PT[wave];

  // stage the whole 96-domain tile once (12 chunks/thread, per-row XOR swizzle)
  #pragma unroll
  for (int c=0;c<12;c++){
    int id2 = tid + c*512;
    int dom = id2 >> 6;
    h8 v = *(const h8*)(dfeat + (size_t)(dbase+dom)*EDIM + (id2&63)*8);
    *(h8*)(DFb + ((id2*16) ^ ((dom&7)<<4))) = v;
  }

  // Q fragments in registers (qrow = wrow + l15)
  h8 q[16];
  {
    const ushort* qr = rfeat + (size_t)(wrow + l15)*EDIM + lhi*8;
    #pragma unroll
    for (int c=0;c<16;c++) q[c] = *(const h8*)(qr + c*32);
  }

  f4 acc[4] = {};
  float m = -1e30f, lsum = 0.f, offa = 0.f;
  const int sb = (lane & 48) + ((lane >> 4) << 2);  // gather src base: lhi*16 + lhi*4

  __syncthreads();   // DF ready; the ONLY block barrier

  for (int t=0; t<TILES; ++t){
    const int d0 = dbase + t*32;
    const int dloc = t*32;

    // swapped QK^T: A = domain fragment (dom = dloc+ct*16+l15), B = q
    f4 SL[2] = {}, SC[2] = {}, SO[2] = {};
    #pragma unroll
    for (int ct=0; ct<2; ++ct){
      const int dom = dloc + ct*16 + l15;
      const int swz = (dom&7)<<4;
      const int base = dom*1024 + lhi*16;
      #pragma unroll
      for (int c=0;c<8;c++){
        h8 b = *(const h8*)(DFb + ((base + c*64) ^ swz));
        SL[ct] = MFMA(b, q[c], SL[ct]);
      }
      #pragma unroll
      for (int c=8;c<12;c++){
        h8 b = *(const h8*)(DFb + ((base + c*64) ^ swz));
        SC[ct] = MFMA(b, q[c], SC[ct]);
      }
      #pragma unroll
      for (int c=12;c<16;c++){
        h8 b = *(const h8*)(DFb + ((base + c*64) ^ swz));
        SO[ct] = MFMA(b, q[c], SO[ct]);
      }
    }

    // lane-local softmax for qrow = l15 (8 doms per lane, spread over lhi)
    float lm = fmaxf(
        fmaxf(fmaxf(SL[0][0],SL[0][1]), fmaxf(SL[0][2],SL[0][3])),
        fmaxf(fmaxf(SL[1][0],SL[1][1]), fmaxf(SL[1][2],SL[1][3]))) * CL;
    lm = fmaxf(lm, __shfl_xor(lm, 16, 64));
    lm = fmaxf(lm, __shfl_xor(lm, 32, 64));   // exact row max, uniform across lhi
    float mn = fmaxf(m, lm);
    float al = __builtin_amdgcn_exp2f(m - mn);
    m = mn;
    lsum *= al; offa *= al;

    us4 w0, w1;
    #pragma unroll
    for (int r=0;r<4;r++){
      float p0 = __builtin_amdgcn_exp2f(SL[0][r]*CL - mn);
      float p1 = __builtin_amdgcn_exp2f(SL[1][r]*CL - mn);
      lsum += p0 + p1;
      float c0 = tanh_fast(SC[0][r]*CH)*1.8f;
      float c1 = tanh_fast(SC[1][r]*CH)*1.8f;
      float o0 = tanh_fast(SO[0][r]*CH);
      float o1 = tanh_fast(SO[1][r]*CH);
      offa += p0*o0 + p1*o1;
      w0[r] = f2h(p0*c0);
      w1[r] = f2h(p1*c1);
    }
    // PT write: row qrow=l15, doms ct*16+lhi*4..+4 as b64, swizzle ^((l15&3)<<4)
    {
      const int wbase = l15*64;
      const int xs = (l15&3)<<4;
      *(us4*)(PTb + ((wbase + lhi*8) ^ xs))      = w0;
      *(us4*)(PTb + ((wbase + 32 + lhi*8) ^ xs)) = w1;
    }

    // pin order: PT writes before PV PT-read (same-wave DS pipe is in-order)
    __builtin_amdgcn_sched_barrier(0);

    // PV: gather al for rows lhi*4+r, rescale acc, then MFMA
    {
      float alr[4];
      #pragma unroll
      for (int r=0;r<4;r++) alr[r] = __shfl(al, sb + r, 64);
      #pragma unroll
      for (int nt=0; nt<4; nt++){
        acc[nt][0]*=alr[0]; acc[nt][1]*=alr[1];
        acc[nt][2]*=alr[2]; acc[nt][3]*=alr[3];
      }
      h8 pa = *(const h8*)(PTb + ((l15*64 + lhi*16) ^ ((l15&3)<<4)));
      #pragma unroll
      for (int nt=0; nt<4; nt++){
        int n = nt*16 + l15;
        h8 vb = *(const h8*)(dflt + (size_t)n*NDB + d0 + lhi*8);
        acc[nt] = MFMA(pa, vb, acc[nt]);
      }
    }

    // pin order: PV PT-read stays before next iteration's PT writes
    __builtin_amdgcn_sched_barrier(0);
  }

  // epilogue: reduce l/off across lhi, store fp16 partials
  float ls = lsum, oa = offa;
  ls += __shfl_xor(ls, 16, 64); ls += __shfl_xor(ls, 32, 64);
  oa += __shfl_xor(oa, 16, 64); oa += __shfl_xor(oa, 32, 64);

  #pragma unroll
  for (int r=0;r<4;r++){
    int row = wrow + lhi*4 + r;
    size_t base = ((size_t)by*NRB + row)*64;
    #pragma unroll
    for (int nt=0; nt<4; nt++){
      accbuf[base + nt*16 + l15] = f2h(acc[nt][r]);
    }
  }
  if (lane < 16){
    size_t mo = ((size_t)by*NRB + wrow + l15)*4;
    mlbuf[mo+0] = m;
    mlbuf[mo+1] = ls;
    mlbuf[mo+2] = oa;
  }
}

// ---------------- combine partials (fp16 accbuf), 16 rows/block = 864 blocks
#define CROWS 16
__global__ __launch_bounds__(256) void combine_kernel(
    const ushort* __restrict__ accbuf,
    const float* __restrict__ mlbuf,
    float* __restrict__ out)
{
  __shared__ float wS[CROWS][SPLIT+1];
  __shared__ float c0S[CROWS], iTS[CROWS];
  const int rb = blockIdx.x;
  const int tid = threadIdx.x;

  if (tid < CROWS){
    int row = rb*CROWS + tid;
    float M = -1e30f;
    float m[SPLIT], l[SPLIT], o[SPLIT];
    #pragma unroll
    for (int s=0;s<SPLIT;s++){
      size_t off = ((size_t)s*NRB + row)*4;
      m[s]=mlbuf[off]; l[s]=mlbuf[off+1]; o[s]=mlbuf[off+2];
      M = fmaxf(M, m[s]);
    }
    float T=0.f, C=0.f;
    #pragma unroll
    for (int s=0;s<SPLIT;s++){
      float w = __builtin_amdgcn_exp2f(m[s]-M);
      wS[tid][s]=w; T += l[s]*w; C += o[s]*w;
    }
    c0S[tid]=C; iTS[tid]=1.0f/T;
  }
  __syncthreads();

  const int row_l = tid>>4;         // 0..15
  const int cb = (tid&15)*4;        // 0..60
  const int row = rb*CROWS + row_l;
  float res[4] = {};
  #pragma unroll
  for (int s=0;s<SPLIT;s++){
    float w = wS[row_l][s];
    hh4 v = *(const hh4*)(accbuf + ((size_t)s*NRB + row)*64 + cb);
    #pragma unroll
    for (int j=0;j<4;j++) res[j] += (float)v[j]*w;
  }
  float C = c0S[row_l], iT = iTS[row_l];
  #pragma unroll
  for (int j=0;j<4;j++) out[(size_t)row*64 + cb + j] = (res[j]+C)*iT;
}

extern "C" void kernel_launch(void* const* d_in, const int* in_sizes, int n_in,
                              void* d_out, int out_size, void* d_ws, size_t ws_size,
                              hipStream_t stream) {
  const float* pooled = (const float*)d_in[0];
  const float* rlat   = (const float*)d_in[1];
  const float* dlat   = (const float*)d_in[2];
  const float* rpos   = (const float*)d_in[3];
  const float* dpos   = (const float*)d_in[4];
  const float* Wrp    = (const float*)d_in[5];
  const float* brp    = (const float*)d_in[6];
  const float* Wdp    = (const float*)d_in[7];
  const float* bdp    = (const float*)d_in[8];
  const float* Wrc    = (const float*)d_in[9];
  const float* brc    = (const float*)d_in[10];
  const float* Wdc    = (const float*)d_in[11];
  const float* bdc    = (const float*)d_in[12];
  const float* Wro    = (const float*)d_in[13];
  const float* bro    = (const float*)d_in[14];
  const float* Wdo2   = (const float*)d_in[15];
  const float* bdo2   = (const float*)d_in[16];

  char* ws = (char*)d_ws;
  size_t off = 0;
  ushort* rb    = (ushort*)(ws + off); off += (size_t)NRB*EDIM*2;
  ushort* db    = (ushort*)(ws + off); off += (size_t)NDB*EDIM*2;
  ushort* Wr_t  = (ushort*)(ws + off); off += (size_t)512*512*2;
  ushort* Wd_t  = (ushort*)(ws + off); off += (size_t)512*512*2;
  float*  br_c  = (float*)(ws + off);  off += 512*4;
  float*  bd_c  = (float*)(ws + off);  off += 512*4;
  ushort* rfeat = (ushort*)(ws + off); off += (size_t)NRB*EDIM*2;
  ushort* dfeat = (ushort*)(ws + off); off += (size_t)NDB*EDIM*2;
  ushort* dflt  = (ushort*)(ws + off); off += (size_t)64*NDB*2;
  ushort* accb  = (ushort*)(ws + off); off += (size_t)SPLIT*NRB*64*2;
  float*  mlb   = (float*)(ws + off);  off += (size_t)SPLIT*NRB*4*4;

  prep_kernel<<<2048, 256, 0, stream>>>(pooled, rlat, dlat, rpos, dpos,
      Wrp, brp, Wdp, bdp, Wrc, brc, Wdc, bdc, Wro, bro, Wdo2, bdo2,
      rb, db, Wr_t, Wd_t, br_c, bd_c, dflt);

  gemm_feats<<<dim3(122,4), 256, 0, stream>>>(rb, Wr_t, br_c, rfeat,
                                              db, Wd_t, bd_c, dfeat);

  attn_kernel<<<NWG, 512, 0, stream>>>(rfeat, dfeat, dflt, accb, mlb);
  combine_kernel<<<NRB/CROWS, 256, 0, stream>>>(accb, mlb, (float*)d_out);
}